// Round 10
// baseline (1394.948 us; speedup 1.0000x reference)
//
#include <hip/hip_runtime.h>

#define N_NODESC 100000
#define N_EDGESC 1600000
#define DIM 128
#define NREL 8
#define KTOT 1152            // W layout: 8*128 relation-K + 128 self-loop K
#define SCAN_CHUNK 2048
#define SCAN_NB 49           // ceil(100000/2048)

typedef __attribute__((ext_vector_type(8))) short short8v;
typedef __attribute__((ext_vector_type(4))) float f32x4;

__device__ __forceinline__ ushort f2bf_rn(float f) {
    uint u = __float_as_uint(f);
    uint r = (u + 0x7FFFu + ((u >> 16) & 1u)) >> 16;   // round-to-nearest-even bf16
    return (ushort)r;
}
__device__ __forceinline__ float bf2f(ushort h) { return __uint_as_float(((uint)h) << 16); }

// ---------------- zero deg/cursor (graph-capture-safe replacement for hipMemsetAsync)
__global__ void k_zero(int* __restrict__ deg, int* __restrict__ cursor) {
    int i = blockIdx.x * blockDim.x + threadIdx.x;
    if (i < N_NODESC) { deg[i] = 0; cursor[i] = 0; }
}

// ---------------- weights: WT_{hi,lo}[col*1152 + k] = split_bf16(Wcat[k][col]); W2c[r*128+i]
__global__ void k_weights(const float* __restrict__ basis1, const float* __restrict__ comb1,
                          const float* __restrict__ basis2, const float* __restrict__ comb2,
                          const float* __restrict__ loop1,
                          ushort* __restrict__ WT_hi, ushort* __restrict__ WT_lo,
                          float* __restrict__ W2c) {
    int idx = blockIdx.x * blockDim.x + threadIdx.x;
    if (idx < KTOT * DIM) {
        int k = idx >> 7;
        int col = idx & (DIM - 1);
        float w;
        if (k < NREL * DIM) {
            int r = k >> 7, i = k & (DIM - 1);
            float acc = 0.f;
#pragma unroll
            for (int b = 0; b < NREL; ++b)
                acc += comb1[r * NREL + b] * basis1[b * DIM * DIM + i * DIM + col];
            w = acc;
        } else {
            w = loop1[(k - NREL * DIM) * DIM + col];
        }
        ushort h = f2bf_rn(w);
        ushort l = f2bf_rn(w - bf2f(h));
        WT_hi[(size_t)col * KTOT + k] = h;
        WT_lo[(size_t)col * KTOT + k] = l;
    }
    if (idx < NREL * DIM) {
        int r = idx >> 7, i = idx & (DIM - 1);
        float acc = 0.f;
#pragma unroll
        for (int b = 0; b < NREL; ++b)
            acc += comb2[r * NREL + b] * basis2[b * DIM + i];
        W2c[idx] = acc;
    }
}

// ---------------- x -> bf16 hi/lo pair (row-major [node][128]); feeds the self-loop GEMM pass
__global__ void k_convx(const float* __restrict__ x, ushort* __restrict__ x_hi,
                        ushort* __restrict__ x_lo) {
    int i = blockIdx.x * blockDim.x + threadIdx.x;   // float4 index
    if (i >= N_NODESC * DIM / 4) return;
    float4 v = ((const float4*)x)[i];
    ushort h0 = f2bf_rn(v.x), h1 = f2bf_rn(v.y), h2 = f2bf_rn(v.z), h3 = f2bf_rn(v.w);
    ushort l0 = f2bf_rn(v.x - bf2f(h0)), l1 = f2bf_rn(v.y - bf2f(h1));
    ushort l2 = f2bf_rn(v.z - bf2f(h2)), l3 = f2bf_rn(v.w - bf2f(h3));
    uint2 hw, lw;
    hw.x = (uint)h0 | ((uint)h1 << 16); hw.y = (uint)h2 | ((uint)h3 << 16);
    lw.x = (uint)l0 | ((uint)l1 << 16); lw.y = (uint)l2 | ((uint)l3 << 16);
    ((uint2*)x_hi)[i] = hw;
    ((uint2*)x_lo)[i] = lw;
}

// ---------------- CSR build (by dst)
__global__ void k_hist(const int* __restrict__ dst, int* __restrict__ deg) {
    int e = blockIdx.x * blockDim.x + threadIdx.x;
    if (e < N_EDGESC) atomicAdd(&deg[dst[e]], 1);
}

__global__ void k_scan1(const int* __restrict__ deg, int* __restrict__ offs, int* __restrict__ partials) {
    __shared__ int sthr[256];
    int blk = blockIdx.x, t = threadIdx.x;
    int base = blk * SCAN_CHUNK + t * 8;
    int v[8];
    int s = 0;
#pragma unroll
    for (int i = 0; i < 8; ++i) {
        int idx = base + i;
        v[i] = (idx < N_NODESC) ? deg[idx] : 0;
        s += v[i];
    }
    sthr[t] = s;
    __syncthreads();
    for (int d = 1; d < 256; d <<= 1) {
        int x = 0;
        if (t >= d) x = sthr[t - d];
        __syncthreads();
        if (t >= d) sthr[t] += x;
        __syncthreads();
    }
    int run = (t == 0) ? 0 : sthr[t - 1];
#pragma unroll
    for (int i = 0; i < 8; ++i) {
        int idx = base + i;
        if (idx < N_NODESC) offs[idx] = run;
        run += v[i];
    }
    if (t == 255) partials[blk] = sthr[255];
}

__global__ void k_scan2(int* __restrict__ partials, int nb) {
    int t = threadIdx.x;  // 64 threads
    int v = (t < nb) ? partials[t] : 0;
    int incl = v;
#pragma unroll
    for (int d = 1; d < 64; d <<= 1) {
        int x = __shfl_up(incl, d);
        if (t >= d) incl += x;
    }
    if (t < nb) partials[t] = incl - v;  // exclusive
}

__global__ void k_scan3(int* __restrict__ offs, const int* __restrict__ partials) {
    int idx = blockIdx.x * blockDim.x + threadIdx.x;
    if (idx < N_NODESC) offs[idx] += partials[idx >> 11];  // /SCAN_CHUNK
    if (idx == 0) offs[N_NODESC] = N_EDGESC;
}

__global__ void k_fill(const int* __restrict__ src, const int* __restrict__ dst,
                       const int* __restrict__ et, const int* __restrict__ offs,
                       int* __restrict__ cursor, int* __restrict__ epk) {
    int e = blockIdx.x * blockDim.x + threadIdx.x;
    if (e < N_EDGESC) {
        int d = dst[e];
        int pos = offs[d] + atomicAdd(&cursor[d], 1);
        epk[pos] = src[e] | (et[e] << 20);
    }
}

// ---------------- scatter (chunked): one wave per dst node; accumulate x[src] rows for
// relations [rbase, rbase+rpc) into fp32 register accumulators, emit bf16 hi/lo S rows
// of width rpc*128. x is 51 MB -> L3-resident; gather is Infinity-Cache-served.
__global__ void k_scatter(const float* __restrict__ x, const int* __restrict__ offs,
                          const int* __restrict__ epk,
                          ushort* __restrict__ S_hi, ushort* __restrict__ S_lo,
                          int rbase, int rpc) {
    int wid = (int)((blockIdx.x * (size_t)blockDim.x + threadIdx.x) >> 6);
    int lane = threadIdx.x & 63;
    if (wid >= N_NODESC) return;
    int beg = offs[wid], end = offs[wid + 1];
    float2 a0 = {0.f, 0.f}, a1 = {0.f, 0.f}, a2 = {0.f, 0.f}, a3 = {0.f, 0.f};
    float2 a4 = {0.f, 0.f}, a5 = {0.f, 0.f}, a6 = {0.f, 0.f}, a7 = {0.f, 0.f};
#pragma unroll 4
    for (int j = beg; j < end; ++j) {
        int v = __builtin_amdgcn_readfirstlane(epk[j]);
        int rl = (v >> 20) - rbase;
        if ((unsigned)rl < (unsigned)rpc) {
            int s = v & 0xFFFFF;
            float2 m = *(const float2*)&x[(size_t)s * DIM + lane * 2];
            switch (rl) {
                case 0: a0.x += m.x; a0.y += m.y; break;
                case 1: a1.x += m.x; a1.y += m.y; break;
                case 2: a2.x += m.x; a2.y += m.y; break;
                case 3: a3.x += m.x; a3.y += m.y; break;
                case 4: a4.x += m.x; a4.y += m.y; break;
                case 5: a5.x += m.x; a5.y += m.y; break;
                case 6: a6.x += m.x; a6.y += m.y; break;
                case 7: a7.x += m.x; a7.y += m.y; break;
            }
        }
    }
    uint* Hp = (uint*)S_hi + (size_t)wid * (rpc * 64);
    uint* Lp = (uint*)S_lo + (size_t)wid * (rpc * 64);
    float2 acc[8] = {a0, a1, a2, a3, a4, a5, a6, a7};
#pragma unroll
    for (int r = 0; r < 8; ++r) {
        if (r < rpc) {
            ushort h0 = f2bf_rn(acc[r].x), h1 = f2bf_rn(acc[r].y);
            ushort l0 = f2bf_rn(acc[r].x - bf2f(h0)), l1 = f2bf_rn(acc[r].y - bf2f(h1));
            Hp[r * 64 + lane] = (uint)h0 | ((uint)h1 << 16);
            Lp[r * 64 + lane] = (uint)l0 | ((uint)l1 << 16);
        }
    }
}

// ---------------- layer-1 GEMM pass via MFMA split-bf16: agg (+)= A * W[kbase:kbase+kw] (+bias)
// A: [100000][kw] bf16 hi/lo, row stride = kw elements. W: WT_{hi,lo}[col*KTOT + k].
// acc ~= A_hi*W_hi + A_hi*W_lo + A_lo*W_hi (lo*lo dropped, ~4e-6 rel).
// 128x128 tile, BK=64, 4 waves (2x2), 64x64/wave, single-buffered 64 KB LDS -> 2 blocks/CU.
// STAGING: REG-STAGED — plain global_load_dwordx4 from LINEAR source into registers, then
// explicit ds_write_b128 at the XOR-swizzled offset (c ^ (row&7)). Both swizzle sides are
// ordinary per-lane LDS addressing; no global_load_lds wave-uniform-dest contract in play
// (fault-surface reduction; ~26% GEMM cost per m151, to be A/B'd back after a pass lands).
// Loads issue BEFORE the barrier -> overlap prior-tile drain. Banks: write 2-way, read 2-way.
__global__ __launch_bounds__(256) void k_gemmc(const ushort* __restrict__ A_hi,
                                               const ushort* __restrict__ A_lo,
                                               const ushort* __restrict__ WT_hi,
                                               const ushort* __restrict__ WT_lo,
                                               const float* __restrict__ bias1,
                                               float* __restrict__ agg,
                                               int kw, int kbase, int first) {
    alignas(16) __shared__ ushort lA_hi[128 * 64];
    alignas(16) __shared__ ushort lA_lo[128 * 64];
    alignas(16) __shared__ ushort lB_hi[128 * 64];
    alignas(16) __shared__ ushort lB_lo[128 * 64];
    const int t = threadIdx.x;
    const int lane = t & 63;
    const int w = t >> 6;      // wave 0..3
    const int wr = w >> 1;     // wave row 0..1 (64 rows each)
    const int wc = w & 1;      // wave col 0..1 (64 cols each)
    const int node0 = blockIdx.x * 128;
    const int l15 = lane & 15;
    const int l4 = lane >> 4;

    // per-thread staging coords: chunk p = j*256 + t -> (row = p>>3, c = p&7)
    int scsw[4];
    size_t goffA[4];
    int goffB[4];
#pragma unroll
    for (int j = 0; j < 4; ++j) {
        int p = j * 256 + t;
        int row = p >> 3;
        int c = p & 7;
        scsw[j] = row * 64 + ((c ^ (row & 7)) << 3);   // swizzled LDS elem offset
        int rowg = node0 + row;
        if (rowg > N_NODESC - 1) rowg = N_NODESC - 1;  // clamp tail reads in-bounds
        goffA[j] = (size_t)rowg * kw + (c << 3);       // linear global source (elem)
        goffB[j] = row * KTOT + kbase + (c << 3);
    }

    f32x4 acc[4][4];
#pragma unroll
    for (int m = 0; m < 4; ++m)
#pragma unroll
        for (int n = 0; n < 4; ++n) acc[m][n] = (f32x4)0.f;

    for (int kc = 0; kc < kw; kc += 64) {
        // issue all global loads for this tile (registers only; overlaps prior-tile compute)
        uint4 rAh[4], rAl[4], rBh[4], rBl[4];
#pragma unroll
        for (int j = 0; j < 4; ++j) {
            rAh[j] = *(const uint4*)(A_hi + goffA[j] + kc);
            rAl[j] = *(const uint4*)(A_lo + goffA[j] + kc);
            rBh[j] = *(const uint4*)(WT_hi + goffB[j] + kc);
            rBl[j] = *(const uint4*)(WT_lo + goffB[j] + kc);
        }
        __syncthreads();  // prev tile's ds_reads complete before overwrite
#pragma unroll
        for (int j = 0; j < 4; ++j) {
            *(uint4*)&lA_hi[scsw[j]] = rAh[j];
            *(uint4*)&lA_lo[scsw[j]] = rAl[j];
            *(uint4*)&lB_hi[scsw[j]] = rBh[j];
            *(uint4*)&lB_lo[scsw[j]] = rBl[j];
        }
        __syncthreads();  // staged data visible to all waves
#pragma unroll
        for (int ks = 0; ks < 2; ++ks) {  // two K=32 sub-steps per 64-K tile
            short8v ah[4], al[4], bh[4], bl[4];
            int cl = ks * 4 + l4;          // k-chunk 0..7 within the tile
#pragma unroll
            for (int m = 0; m < 4; ++m) {
                int row = wr * 64 + m * 16 + l15;
                int off = row * 64 + ((cl ^ (row & 7)) << 3);
                ah[m] = *(const short8v*)&lA_hi[off];
                al[m] = *(const short8v*)&lA_lo[off];
            }
#pragma unroll
            for (int n = 0; n < 4; ++n) {
                int row = wc * 64 + n * 16 + l15;   // = W output column
                int off = row * 64 + ((cl ^ (row & 7)) << 3);
                bh[n] = *(const short8v*)&lB_hi[off];
                bl[n] = *(const short8v*)&lB_lo[off];
            }
#pragma unroll
            for (int m = 0; m < 4; ++m)
#pragma unroll
                for (int n = 0; n < 4; ++n) {
                    acc[m][n] = __builtin_amdgcn_mfma_f32_16x16x32_bf16(ah[m], bh[n], acc[m][n], 0, 0, 0);
                    acc[m][n] = __builtin_amdgcn_mfma_f32_16x16x32_bf16(ah[m], bl[n], acc[m][n], 0, 0, 0);
                    acc[m][n] = __builtin_amdgcn_mfma_f32_16x16x32_bf16(al[m], bh[n], acc[m][n], 0, 0, 0);
                }
        }
    }

    // epilogue: C[row=(lane>>4)*4+q][col=lane&15] per 16x16 fragment (m89-verified layout)
#pragma unroll
    for (int n = 0; n < 4; ++n) {
        int col = wc * 64 + n * 16 + l15;
        float bv = first ? bias1[col] : 0.f;
#pragma unroll
        for (int m = 0; m < 4; ++m) {
            int row0 = node0 + wr * 64 + m * 16 + (l4 << 2);
#pragma unroll
            for (int q = 0; q < 4; ++q) {
                int row = row0 + q;
                if (row < N_NODESC) {
                    size_t idx = (size_t)row * DIM + col;
                    float v = acc[m][n][q] + bv;
                    if (!first) v += agg[idx];
                    agg[idx] = v;
                }
            }
        }
    }
}

// ---------------- ReLU + layer-2 projections (9 dots per node), init out with self-loop part
__global__ void k_layer2a(const float* __restrict__ agg, const float* __restrict__ W2c,
                          const float* __restrict__ loop2, const float* __restrict__ bias2,
                          float* __restrict__ proj2, float* __restrict__ out) {
    int wid = (int)((blockIdx.x * (size_t)blockDim.x + threadIdx.x) >> 6);
    int lane = threadIdx.x & 63;
    if (wid >= N_NODESC) return;
    float2 hv = *(const float2*)&agg[(size_t)wid * DIM + lane * 2];
    hv.x = fmaxf(hv.x, 0.f);
    hv.y = fmaxf(hv.y, 0.f);
    float p[9];
#pragma unroll
    for (int r = 0; r < NREL; ++r) {
        float2 w = *(const float2*)&W2c[r * DIM + lane * 2];
        p[r] = hv.x * w.x + hv.y * w.y;
    }
    {
        float2 w = *(const float2*)&loop2[lane * 2];
        p[8] = hv.x * w.x + hv.y * w.y;
    }
#pragma unroll
    for (int r = 0; r < 9; ++r) {
#pragma unroll
        for (int d = 1; d < 64; d <<= 1) p[r] += __shfl_xor(p[r], d);
    }
    if (lane == 0) {
        float* pp = proj2 + (size_t)wid * NREL;
        *(float4*)&pp[0] = make_float4(p[0], p[1], p[2], p[3]);
        *(float4*)&pp[4] = make_float4(p[4], p[5], p[6], p[7]);
        out[wid] = p[8] + bias2[0];
    }
}

// ---------------- layer-2 edge pass: thread per destination, scalar sum (proj2 3.2 MB -> L2/L3)
__global__ void k_out(const float* __restrict__ proj2, const int* __restrict__ offs,
                      const int* __restrict__ epk, float* __restrict__ out) {
    int d = blockIdx.x * blockDim.x + threadIdx.x;
    if (d >= N_NODESC) return;
    int beg = offs[d], end = offs[d + 1];
    float s = 0.f;
#pragma unroll 4
    for (int j = beg; j < end; ++j) {
        int v = epk[j];
        s += proj2[(size_t)(v & 0xFFFFF) * NREL + (v >> 20)];
    }
    out[d] += s;
}

extern "C" void kernel_launch(void* const* d_in, const int* in_sizes, int n_in,
                              void* d_out, int out_size, void* d_ws, size_t ws_size,
                              hipStream_t stream) {
    const float* x = (const float*)d_in[0];
    const int* src = (const int*)d_in[1];
    const int* dst = (const int*)d_in[2];
    const int* et = (const int*)d_in[3];
    const float* basis1 = (const float*)d_in[4];
    const float* comb1 = (const float*)d_in[5];
    const float* loop1 = (const float*)d_in[6];
    const float* bias1 = (const float*)d_in[7];
    const float* basis2 = (const float*)d_in[8];
    const float* comb2 = (const float*)d_in[9];
    const float* loop2 = (const float*)d_in[10];
    const float* bias2 = (const float*)d_in[11];
    float* out = (float*)d_out;

    const size_t M = N_NODESC;
    // misc footprint (everything except the S pair), incl. per-buffer 256B pads:
    const size_t misc = 2 * (M * DIM * 2)      // x_hi, x_lo            (51.2 MB)
                      + M * DIM * 4            // agg                   (51.2 MB)
                      + 2 * ((size_t)KTOT * DIM * 2)  // WT_hi, WT_lo   (0.6 MB)
                      + NREL * DIM * 4         // W2c
                      + M * NREL * 4           // proj2                 (3.2 MB)
                      + 3 * M * 4 + 4          // deg, cursor, offs     (1.2 MB)
                      + 64 * 4                 // partials
                      + (size_t)N_EDGESC * 4   // epk                   (6.4 MB)
                      + 16 * 256;              // alignment slack (15 buffers padded)
    // Pick the largest relations-per-chunk whose footprint fits ws_size.
    // Depends only on ws_size (constant per session) -> identical work every call (graph-safe).
    // Footprints: rpc=8 -> 523 MB, 4 -> 318 MB, 2 -> 216 MB, 1 -> 165 MB.
    int rpc = 1;
    for (int cand = 8; cand >= 1; cand >>= 1) {
        size_t need = 2 * (M * (size_t)cand * DIM * 2) + misc;
        if (need <= ws_size) { rpc = cand; break; }
    }
    const int nchunk = NREL / rpc;

    char* p = (char*)d_ws;
    auto alloc = [&](size_t bytes) {
        char* r = p;
        p += (bytes + 255) & ~(size_t)255;
        return r;
    };
    ushort* S_hi = (ushort*)alloc(sizeof(ushort) * M * (size_t)rpc * DIM);  // <= 204.8 MB
    ushort* S_lo = (ushort*)alloc(sizeof(ushort) * M * (size_t)rpc * DIM);
    ushort* x_hi = (ushort*)alloc(sizeof(ushort) * M * DIM);                // 25.6 MB
    ushort* x_lo = (ushort*)alloc(sizeof(ushort) * M * DIM);
    float* agg = (float*)alloc(sizeof(float) * M * DIM);                    // 51.2 MB
    ushort* WT_hi = (ushort*)alloc(sizeof(ushort) * KTOT * DIM);            // 294.9 KB
    ushort* WT_lo = (ushort*)alloc(sizeof(ushort) * KTOT * DIM);
    float* W2c = (float*)alloc(sizeof(float) * NREL * DIM);
    float* proj2 = (float*)alloc(sizeof(float) * M * NREL);                 // 3.2 MB
    int* deg = (int*)alloc(sizeof(int) * N_NODESC);
    int* offs = (int*)alloc(sizeof(int) * (N_NODESC + 1));
    int* partials = (int*)alloc(sizeof(int) * 64);
    int* cursor = (int*)alloc(sizeof(int) * N_NODESC);
    int* epk = (int*)alloc(sizeof(int) * N_EDGESC);

    k_zero<<<(N_NODESC + 255) / 256, 256, 0, stream>>>(deg, cursor);
    k_weights<<<(KTOT * DIM + 255) / 256, 256, 0, stream>>>(basis1, comb1, basis2, comb2, loop1,
                                                            WT_hi, WT_lo, W2c);
    k_convx<<<(N_NODESC * DIM / 4 + 255) / 256, 256, 0, stream>>>(x, x_hi, x_lo);
    k_hist<<<(N_EDGESC + 255) / 256, 256, 0, stream>>>(dst, deg);
    k_scan1<<<SCAN_NB, 256, 0, stream>>>(deg, offs, partials);
    k_scan2<<<1, 64, 0, stream>>>(partials, SCAN_NB);
    k_scan3<<<(N_NODESC + 255) / 256, 256, 0, stream>>>(offs, partials);
    k_fill<<<(N_EDGESC + 255) / 256, 256, 0, stream>>>(src, dst, et, offs, cursor, epk);

    const int ggrid = (N_NODESC + 127) / 128;
    for (int g = 0; g < nchunk; ++g) {
        k_scatter<<<(N_NODESC * 64 + 255) / 256, 256, 0, stream>>>(x, offs, epk, S_hi, S_lo,
                                                                   g * rpc, rpc);
        k_gemmc<<<ggrid, 256, 0, stream>>>(S_hi, S_lo, WT_hi, WT_lo, bias1, agg,
                                           rpc * DIM, g * rpc * DIM, g == 0 ? 1 : 0);
    }
    // self-loop pass: A = x (bf16 pair), W rows [1024,1152)
    k_gemmc<<<ggrid, 256, 0, stream>>>(x_hi, x_lo, WT_hi, WT_lo, bias1, agg,
                                       DIM, NREL * DIM, 0);

    k_layer2a<<<(N_NODESC * 64 + 255) / 256, 256, 0, stream>>>(agg, W2c, loop2, bias2, proj2, out);
    k_out<<<(N_NODESC + 255) / 256, 256, 0, stream>>>(proj2, offs, epk, out);
}

// Round 11
// 1108.727 us; speedup vs baseline: 1.2582x; 1.2582x over previous
//
#include <hip/hip_runtime.h>

#define N_NODESC 100000
#define N_EDGESC 1600000
#define DIM 128
#define NREL 8
#define KTOT 1152            // S row: 8*128 relation-K + 128 self-loop K
#define SCAN_CHUNK 2048
#define SCAN_NB 49           // ceil(100000/2048)

typedef __attribute__((ext_vector_type(8))) short short8v;
typedef __attribute__((ext_vector_type(4))) float f32x4;

__device__ __forceinline__ ushort f2bf_rn(float f) {
    uint u = __float_as_uint(f);
    uint r = (u + 0x7FFFu + ((u >> 16) & 1u)) >> 16;   // round-to-nearest-even bf16
    return (ushort)r;
}
__device__ __forceinline__ float bf2f(ushort h) { return __uint_as_float(((uint)h) << 16); }

// ---------------- zero deg/cursor (graph-capture-safe)
__global__ void k_zero(int* __restrict__ deg, int* __restrict__ cursor) {
    int i = blockIdx.x * blockDim.x + threadIdx.x;
    if (i < N_NODESC) { deg[i] = 0; cursor[i] = 0; }
}

// ---------------- weights: WT_{hi,lo}[col*1152 + k] = split_bf16(Wcat[k][col]); W2c[r*128+i]
__global__ void k_weights(const float* __restrict__ basis1, const float* __restrict__ comb1,
                          const float* __restrict__ basis2, const float* __restrict__ comb2,
                          const float* __restrict__ loop1,
                          ushort* __restrict__ WT_hi, ushort* __restrict__ WT_lo,
                          float* __restrict__ W2c) {
    int idx = blockIdx.x * blockDim.x + threadIdx.x;
    if (idx < KTOT * DIM) {
        int k = idx >> 7;
        int col = idx & (DIM - 1);
        float w;
        if (k < NREL * DIM) {
            int r = k >> 7, i = k & (DIM - 1);
            float acc = 0.f;
#pragma unroll
            for (int b = 0; b < NREL; ++b)
                acc += comb1[r * NREL + b] * basis1[b * DIM * DIM + i * DIM + col];
            w = acc;
        } else {
            w = loop1[(k - NREL * DIM) * DIM + col];
        }
        ushort h = f2bf_rn(w);
        ushort l = f2bf_rn(w - bf2f(h));
        WT_hi[(size_t)col * KTOT + k] = h;
        WT_lo[(size_t)col * KTOT + k] = l;
    }
    if (idx < NREL * DIM) {
        int r = idx >> 7, i = idx & (DIM - 1);
        float acc = 0.f;
#pragma unroll
        for (int b = 0; b < NREL; ++b)
            acc += comb2[r * NREL + b] * basis2[b * DIM + i];
        W2c[idx] = acc;
    }
}

// ---------------- CSR build (by dst)
__global__ void k_hist(const int* __restrict__ dst, int* __restrict__ deg) {
    int e = blockIdx.x * blockDim.x + threadIdx.x;
    if (e < N_EDGESC) atomicAdd(&deg[dst[e]], 1);
}

__global__ void k_scan1(const int* __restrict__ deg, int* __restrict__ offs, int* __restrict__ partials) {
    __shared__ int sthr[256];
    int blk = blockIdx.x, t = threadIdx.x;
    int base = blk * SCAN_CHUNK + t * 8;
    int v[8];
    int s = 0;
#pragma unroll
    for (int i = 0; i < 8; ++i) {
        int idx = base + i;
        v[i] = (idx < N_NODESC) ? deg[idx] : 0;
        s += v[i];
    }
    sthr[t] = s;
    __syncthreads();
    for (int d = 1; d < 256; d <<= 1) {
        int x = 0;
        if (t >= d) x = sthr[t - d];
        __syncthreads();
        if (t >= d) sthr[t] += x;
        __syncthreads();
    }
    int run = (t == 0) ? 0 : sthr[t - 1];
#pragma unroll
    for (int i = 0; i < 8; ++i) {
        int idx = base + i;
        if (idx < N_NODESC) offs[idx] = run;
        run += v[i];
    }
    if (t == 255) partials[blk] = sthr[255];
}

__global__ void k_scan2(int* __restrict__ partials, int nb) {
    int t = threadIdx.x;  // 64 threads
    int v = (t < nb) ? partials[t] : 0;
    int incl = v;
#pragma unroll
    for (int d = 1; d < 64; d <<= 1) {
        int x = __shfl_up(incl, d);
        if (t >= d) incl += x;
    }
    if (t < nb) partials[t] = incl - v;  // exclusive
}

__global__ void k_scan3(int* __restrict__ offs, const int* __restrict__ partials) {
    int idx = blockIdx.x * blockDim.x + threadIdx.x;
    if (idx < N_NODESC) offs[idx] += partials[idx >> 11];  // /SCAN_CHUNK
    if (idx == 0) offs[N_NODESC] = N_EDGESC;
}

__global__ void k_fill(const int* __restrict__ src, const int* __restrict__ dst,
                       const int* __restrict__ et, const int* __restrict__ offs,
                       int* __restrict__ cursor, int* __restrict__ epk) {
    int e = blockIdx.x * blockDim.x + threadIdx.x;
    if (e < N_EDGESC) {
        int d = dst[e];
        int pos = offs[d] + atomicAdd(&cursor[d], 1);
        epk[pos] = src[e] | (et[e] << 20);
    }
}

// ---------------- scatter (M-chunked): one wave per dst node in [clo, clo+cn).
// Accumulates x[src] rows for ALL 8 relations (single edge scan) into fp32 registers,
// then emits the node's full S row (K=1152: 8 rel blocks + self-loop x block) as
// bf16 hi/lo pairs at node-LOCAL row index. x is 51 MB -> L3-resident gather.
__global__ void k_scatter(const float* __restrict__ x, const int* __restrict__ offs,
                          const int* __restrict__ epk,
                          ushort* __restrict__ S_hi, ushort* __restrict__ S_lo,
                          int clo, int cn) {
    int widl = (int)((blockIdx.x * (size_t)blockDim.x + threadIdx.x) >> 6);
    int lane = threadIdx.x & 63;
    if (widl >= cn) return;
    int wid = clo + widl;
    int beg = offs[wid], end = offs[wid + 1];
    float2 a0 = {0.f, 0.f}, a1 = {0.f, 0.f}, a2 = {0.f, 0.f}, a3 = {0.f, 0.f};
    float2 a4 = {0.f, 0.f}, a5 = {0.f, 0.f}, a6 = {0.f, 0.f}, a7 = {0.f, 0.f};
#pragma unroll 4
    for (int j = beg; j < end; ++j) {
        int v = __builtin_amdgcn_readfirstlane(epk[j]);
        int s = v & 0xFFFFF;
        int r = v >> 20;
        float2 m = *(const float2*)&x[(size_t)s * DIM + lane * 2];
        switch (r) {
            case 0: a0.x += m.x; a0.y += m.y; break;
            case 1: a1.x += m.x; a1.y += m.y; break;
            case 2: a2.x += m.x; a2.y += m.y; break;
            case 3: a3.x += m.x; a3.y += m.y; break;
            case 4: a4.x += m.x; a4.y += m.y; break;
            case 5: a5.x += m.x; a5.y += m.y; break;
            case 6: a6.x += m.x; a6.y += m.y; break;
            case 7: a7.x += m.x; a7.y += m.y; break;
        }
    }
    uint* Hp = (uint*)S_hi + (size_t)widl * (KTOT / 2);
    uint* Lp = (uint*)S_lo + (size_t)widl * (KTOT / 2);
    float2 acc[8] = {a0, a1, a2, a3, a4, a5, a6, a7};
#pragma unroll
    for (int r = 0; r < NREL; ++r) {
        ushort h0 = f2bf_rn(acc[r].x), h1 = f2bf_rn(acc[r].y);
        ushort l0 = f2bf_rn(acc[r].x - bf2f(h0)), l1 = f2bf_rn(acc[r].y - bf2f(h1));
        Hp[r * 64 + lane] = (uint)h0 | ((uint)h1 << 16);
        Lp[r * 64 + lane] = (uint)l0 | ((uint)l1 << 16);
    }
    {   // self-loop x row at k = 1024..1151
        float2 m = *(const float2*)&x[(size_t)wid * DIM + lane * 2];
        ushort h0 = f2bf_rn(m.x), h1 = f2bf_rn(m.y);
        ushort l0 = f2bf_rn(m.x - bf2f(h0)), l1 = f2bf_rn(m.y - bf2f(h1));
        Hp[512 + lane] = (uint)h0 | ((uint)h1 << 16);
        Lp[512 + lane] = (uint)l0 | ((uint)l1 << 16);
    }
}

// ---------------- layer-1 GEMM (M-chunked, FULL K=1152, register accumulator, no RMW):
// agg[clo+row][:] = S_local * Wcat + bias1. A,W row stride both KTOT.
// acc ~= A_hi*W_hi + A_hi*W_lo + A_lo*W_hi (lo*lo dropped, ~4e-6 rel).
// 128x128 tile, BK=64, 4 waves (2x2), 64x64/wave, single-buffered 64 KB LDS.
// STAGING: reg-staged (proven r10): global_load_dwordx4 linear -> ds_write_b128 at the
// XOR-swizzled offset (c ^ (row&7)); fragment ds_reads use the same XOR. Banks: 2-way (free).
__global__ __launch_bounds__(256) void k_gemmf(const ushort* __restrict__ A_hi,
                                               const ushort* __restrict__ A_lo,
                                               const ushort* __restrict__ WT_hi,
                                               const ushort* __restrict__ WT_lo,
                                               const float* __restrict__ bias1,
                                               float* __restrict__ agg,
                                               int clo, int cn) {
    alignas(16) __shared__ ushort lA_hi[128 * 64];
    alignas(16) __shared__ ushort lA_lo[128 * 64];
    alignas(16) __shared__ ushort lB_hi[128 * 64];
    alignas(16) __shared__ ushort lB_lo[128 * 64];
    const int t = threadIdx.x;
    const int lane = t & 63;
    const int w = t >> 6;      // wave 0..3
    const int wr = w >> 1;     // wave row 0..1 (64 rows each)
    const int wc = w & 1;      // wave col 0..1 (64 cols each)
    const int node0 = blockIdx.x * 128;   // chunk-local
    const int l15 = lane & 15;
    const int l4 = lane >> 4;

    // per-thread staging coords: chunk p = j*256 + t -> (row = p>>3, c = p&7)
    int scsw[4];
    size_t goffA[4];
    int goffB[4];
#pragma unroll
    for (int j = 0; j < 4; ++j) {
        int p = j * 256 + t;
        int row = p >> 3;
        int c = p & 7;
        scsw[j] = row * 64 + ((c ^ (row & 7)) << 3);   // swizzled LDS elem offset
        int rowl = node0 + row;
        if (rowl > cn - 1) rowl = cn - 1;              // clamp tail reads in-bounds
        goffA[j] = (size_t)rowl * KTOT + (c << 3);     // linear global source (elem)
        goffB[j] = row * KTOT + (c << 3);
    }

    f32x4 acc[4][4];
#pragma unroll
    for (int m = 0; m < 4; ++m)
#pragma unroll
        for (int n = 0; n < 4; ++n) acc[m][n] = (f32x4)0.f;

    for (int kc = 0; kc < KTOT; kc += 64) {
        // issue all global loads for this tile (registers only; overlaps prior-tile compute)
        uint4 rAh[4], rAl[4], rBh[4], rBl[4];
#pragma unroll
        for (int j = 0; j < 4; ++j) {
            rAh[j] = *(const uint4*)(A_hi + goffA[j] + kc);
            rAl[j] = *(const uint4*)(A_lo + goffA[j] + kc);
            rBh[j] = *(const uint4*)(WT_hi + goffB[j] + kc);
            rBl[j] = *(const uint4*)(WT_lo + goffB[j] + kc);
        }
        __syncthreads();  // prev tile's ds_reads complete before overwrite
#pragma unroll
        for (int j = 0; j < 4; ++j) {
            *(uint4*)&lA_hi[scsw[j]] = rAh[j];
            *(uint4*)&lA_lo[scsw[j]] = rAl[j];
            *(uint4*)&lB_hi[scsw[j]] = rBh[j];
            *(uint4*)&lB_lo[scsw[j]] = rBl[j];
        }
        __syncthreads();  // staged data visible to all waves
#pragma unroll
        for (int ks = 0; ks < 2; ++ks) {  // two K=32 sub-steps per 64-K tile
            short8v ah[4], al[4], bh[4], bl[4];
            int cl = ks * 4 + l4;          // k-chunk 0..7 within the tile
#pragma unroll
            for (int m = 0; m < 4; ++m) {
                int row = wr * 64 + m * 16 + l15;
                int off = row * 64 + ((cl ^ (row & 7)) << 3);
                ah[m] = *(const short8v*)&lA_hi[off];
                al[m] = *(const short8v*)&lA_lo[off];
            }
#pragma unroll
            for (int n = 0; n < 4; ++n) {
                int row = wc * 64 + n * 16 + l15;   // = W output column
                int off = row * 64 + ((cl ^ (row & 7)) << 3);
                bh[n] = *(const short8v*)&lB_hi[off];
                bl[n] = *(const short8v*)&lB_lo[off];
            }
#pragma unroll
            for (int m = 0; m < 4; ++m)
#pragma unroll
                for (int n = 0; n < 4; ++n) {
                    acc[m][n] = __builtin_amdgcn_mfma_f32_16x16x32_bf16(ah[m], bh[n], acc[m][n], 0, 0, 0);
                    acc[m][n] = __builtin_amdgcn_mfma_f32_16x16x32_bf16(ah[m], bl[n], acc[m][n], 0, 0, 0);
                    acc[m][n] = __builtin_amdgcn_mfma_f32_16x16x32_bf16(al[m], bh[n], acc[m][n], 0, 0, 0);
                }
        }
    }

    // epilogue: C[row=(lane>>4)*4+q][col=lane&15] per 16x16 fragment; single write, no RMW
#pragma unroll
    for (int n = 0; n < 4; ++n) {
        int col = wc * 64 + n * 16 + l15;
        float bv = bias1[col];
#pragma unroll
        for (int m = 0; m < 4; ++m) {
            int lrow0 = node0 + wr * 64 + m * 16 + (l4 << 2);
#pragma unroll
            for (int q = 0; q < 4; ++q) {
                int lrow = lrow0 + q;
                if (lrow < cn)
                    agg[(size_t)(clo + lrow) * DIM + col] = acc[m][n][q] + bv;
            }
        }
    }
}

// ---------------- ReLU + layer-2 projections (9 dots per node), init out with self-loop part
__global__ void k_layer2a(const float* __restrict__ agg, const float* __restrict__ W2c,
                          const float* __restrict__ loop2, const float* __restrict__ bias2,
                          float* __restrict__ proj2, float* __restrict__ out) {
    int wid = (int)((blockIdx.x * (size_t)blockDim.x + threadIdx.x) >> 6);
    int lane = threadIdx.x & 63;
    if (wid >= N_NODESC) return;
    float2 hv = *(const float2*)&agg[(size_t)wid * DIM + lane * 2];
    hv.x = fmaxf(hv.x, 0.f);
    hv.y = fmaxf(hv.y, 0.f);
    float p[9];
#pragma unroll
    for (int r = 0; r < NREL; ++r) {
        float2 w = *(const float2*)&W2c[r * DIM + lane * 2];
        p[r] = hv.x * w.x + hv.y * w.y;
    }
    {
        float2 w = *(const float2*)&loop2[lane * 2];
        p[8] = hv.x * w.x + hv.y * w.y;
    }
#pragma unroll
    for (int r = 0; r < 9; ++r) {
#pragma unroll
        for (int d = 1; d < 64; d <<= 1) p[r] += __shfl_xor(p[r], d);
    }
    if (lane == 0) {
        float* pp = proj2 + (size_t)wid * NREL;
        *(float4*)&pp[0] = make_float4(p[0], p[1], p[2], p[3]);
        *(float4*)&pp[4] = make_float4(p[4], p[5], p[6], p[7]);
        out[wid] = p[8] + bias2[0];
    }
}

// ---------------- layer-2 edge pass: thread per destination, scalar sum (proj2 3.2 MB -> L2/L3)
__global__ void k_out(const float* __restrict__ proj2, const int* __restrict__ offs,
                      const int* __restrict__ epk, float* __restrict__ out) {
    int d = blockIdx.x * blockDim.x + threadIdx.x;
    if (d >= N_NODESC) return;
    int beg = offs[d], end = offs[d + 1];
    float s = 0.f;
#pragma unroll 4
    for (int j = beg; j < end; ++j) {
        int v = epk[j];
        s += proj2[(size_t)(v & 0xFFFFF) * NREL + (v >> 20)];
    }
    out[d] += s;
}

extern "C" void kernel_launch(void* const* d_in, const int* in_sizes, int n_in,
                              void* d_out, int out_size, void* d_ws, size_t ws_size,
                              hipStream_t stream) {
    const float* x = (const float*)d_in[0];
    const int* src = (const int*)d_in[1];
    const int* dst = (const int*)d_in[2];
    const int* et = (const int*)d_in[3];
    const float* basis1 = (const float*)d_in[4];
    const float* comb1 = (const float*)d_in[5];
    const float* loop1 = (const float*)d_in[6];
    const float* bias1 = (const float*)d_in[7];
    const float* basis2 = (const float*)d_in[8];
    const float* comb2 = (const float*)d_in[9];
    const float* loop2 = (const float*)d_in[10];
    const float* bias2 = (const float*)d_in[11];
    float* out = (float*)d_out;

    const size_t M = N_NODESC;
    // misc footprint (everything except the S pair), incl. per-buffer 256B pads:
    const size_t misc = M * DIM * 4            // agg                   (51.2 MB)
                      + 2 * ((size_t)KTOT * DIM * 2)  // WT_hi, WT_lo   (0.6 MB)
                      + NREL * DIM * 4         // W2c
                      + M * NREL * 4           // proj2                 (3.2 MB)
                      + 3 * M * 4 + 4          // deg, cursor, offs     (1.2 MB)
                      + 64 * 4                 // partials
                      + (size_t)N_EDGESC * 4   // epk                   (6.4 MB)
                      + 16 * 256;              // alignment slack
    // nodes-per-chunk: largest multiple of 128 whose S pair (4608 B/node) fits.
    // Deterministic from ws_size (constant per session) -> graph-safe.
    long npc = 128;
    if (ws_size > misc) {
        long cap = (long)((ws_size - misc) / (KTOT * 2 * 2));  // nodes that fit
        cap = (cap / 128) * 128;
        if (cap > 100096) cap = 100096;
        if (cap > npc) npc = cap;
    }
    const int nch = (int)((N_NODESC + npc - 1) / npc);

    char* p = (char*)d_ws;
    auto alloc = [&](size_t bytes) {
        char* r = p;
        p += (bytes + 255) & ~(size_t)255;
        return r;
    };
    ushort* S_hi = (ushort*)alloc(sizeof(ushort) * (size_t)npc * KTOT);  // <= ~115 MB
    ushort* S_lo = (ushort*)alloc(sizeof(ushort) * (size_t)npc * KTOT);
    float* agg = (float*)alloc(sizeof(float) * M * DIM);                 // 51.2 MB
    ushort* WT_hi = (ushort*)alloc(sizeof(ushort) * KTOT * DIM);         // 294.9 KB
    ushort* WT_lo = (ushort*)alloc(sizeof(ushort) * KTOT * DIM);
    float* W2c = (float*)alloc(sizeof(float) * NREL * DIM);
    float* proj2 = (float*)alloc(sizeof(float) * M * NREL);              // 3.2 MB
    int* deg = (int*)alloc(sizeof(int) * N_NODESC);
    int* offs = (int*)alloc(sizeof(int) * (N_NODESC + 1));
    int* partials = (int*)alloc(sizeof(int) * 64);
    int* cursor = (int*)alloc(sizeof(int) * N_NODESC);
    int* epk = (int*)alloc(sizeof(int) * N_EDGESC);

    k_zero<<<(N_NODESC + 255) / 256, 256, 0, stream>>>(deg, cursor);
    k_weights<<<(KTOT * DIM + 255) / 256, 256, 0, stream>>>(basis1, comb1, basis2, comb2, loop1,
                                                            WT_hi, WT_lo, W2c);
    k_hist<<<(N_EDGESC + 255) / 256, 256, 0, stream>>>(dst, deg);
    k_scan1<<<SCAN_NB, 256, 0, stream>>>(deg, offs, partials);
    k_scan2<<<1, 64, 0, stream>>>(partials, SCAN_NB);
    k_scan3<<<(N_NODESC + 255) / 256, 256, 0, stream>>>(offs, partials);
    k_fill<<<(N_EDGESC + 255) / 256, 256, 0, stream>>>(src, dst, et, offs, cursor, epk);

    for (int c = 0; c < nch; ++c) {
        int clo = (int)(c * npc);
        int cn = (int)((N_NODESC - clo < npc) ? (N_NODESC - clo) : npc);
        k_scatter<<<((size_t)cn * 64 + 255) / 256, 256, 0, stream>>>(x, offs, epk,
                                                                     S_hi, S_lo, clo, cn);
        k_gemmf<<<(cn + 127) / 128, 256, 0, stream>>>(S_hi, S_lo, WT_hi, WT_lo, bias1, agg,
                                                      clo, cn);
    }

    k_layer2a<<<(N_NODESC * 64 + 255) / 256, 256, 0, stream>>>(agg, W2c, loop2, bias2, proj2, out);
    k_out<<<(N_NODESC + 255) / 256, 256, 0, stream>>>(proj2, offs, epk, out);
}